// Round 5
// baseline (349.823 us; speedup 1.0000x reference)
//
#include <hip/hip_runtime.h>
#include <math.h>

#define DIMC 1024
#define SEQ 4096
#define BATCH 4
#define NH 16
#define HD 64
#define MTOT (BATCH * SEQ)      // 16384 rows
#define NSPLIT 8
#define PELEMS (64 * 64 * 64 + 64 * 64)   // KV partial + Z partial per split
#define EPS 1e-6f
#define NKT (DIMC / 64)         // 16 K-tiles of 64

typedef __bf16 bf16x8 __attribute__((ext_vector_type(8)));
typedef __bf16 bf16x4 __attribute__((ext_vector_type(4)));
typedef __bf16 bf16x2 __attribute__((ext_vector_type(2)));
typedef float  f32x4  __attribute__((ext_vector_type(4)));

#define MFMA16 __builtin_amdgcn_mfma_f32_16x16x32_bf16

__device__ __forceinline__ float phi_f(float x) {
    return x > 0.0f ? x + 1.0f : __expf(x);   // elu(x)+1
}

// ---------------------------------------------------------------------------
// One-shot fp32->bf16 conversion of x + all 4 weight matrices.
// ---------------------------------------------------------------------------
__global__ __launch_bounds__(256) void cvt_all(
    const float* __restrict__ x,
    const float* __restrict__ Wq, const float* __restrict__ Wk,
    const float* __restrict__ Wv, const float* __restrict__ Wo,
    __bf16* __restrict__ xb,
    __bf16* __restrict__ Wqb, __bf16* __restrict__ Wkb,
    __bf16* __restrict__ Wvb, __bf16* __restrict__ Wob)
{
    const size_t big = (size_t)MTOT * DIMC;
    const size_t wsz = (size_t)DIMC * DIMC;
    size_t i = ((size_t)blockIdx.x * 256 + threadIdx.x) * 4;
    const float* src; __bf16* dst; size_t off;
    if (i < big) { src = x; dst = xb; off = i; }
    else {
        size_t j = i - big;
        int w = (int)(j >> 20);            // /wsz (2^20)
        off = j & (wsz - 1);
        switch (w) {
            case 0: src = Wq; dst = Wqb; break;
            case 1: src = Wk; dst = Wkb; break;
            case 2: src = Wv; dst = Wvb; break;
            default: src = Wo; dst = Wob; break;
        }
    }
    float4 v = *(const float4*)(src + off);
    bf16x4 o = { (__bf16)v.x, (__bf16)v.y, (__bf16)v.z, (__bf16)v.w };
    *(bf16x4*)(dst + off) = o;
}

// ---------------------------------------------------------------------------
// R5: 128x128 4-wave BK=64 GEMM tile, same 8-phase counted-vmcnt schedule as
// the R4 256x256 version but with 64 KiB LDS -> 2 BLOCKS/CU. Rationale (R4
// counters): at 1 block/CU every barrier/waitcnt stall is globally exposed
// (MfmaUtil 39% vs ~80% LDS ceiling); a co-resident second block runs through
// the other's stalls (the m97 mechanism) and round boundaries overlap.
//
// LDS: 2 buf x {A,B} x [128][64] bf16 = 64 KiB. Staging granularity: quarter
// tiles (32 rows = one 256-lane global_load_lds issue, per-wave dest base).
// Swizzle: linear LDS dest + pre-swizzled GLOBAL source column block
// (blk ^= row&7) + same XOR on ds_read (rule #21; R1: conflicts 1.26e7 -> 0).
//
// Per K-tile t (4 phases):
//   ph1: ds_read a01/b01 (8); stage A-q2,q3(t+1) into buf^1
//   ph2: ds_read b23 (4)
//   ph3: ds_read a23 (4);     stage B-q0,q1(t+2) into buf
//   ph4: reg-only MFMA;       stage B-q2,q3,A-q0,q1(t+2); vmcnt(6)
// WAR proof (quarter granularity): A-q2/q3(buf^1) last read completes by
// ph3-end(t-1) < ph1(t); B-q0/q1(buf) by ph2-end(t) < ph3(t); B-q2/q3 and
// A-q0/q1(buf) by ph2/ph3-end(t) < ph4(t). vmcnt(6) at ph4(t) retires
// through A-q3(t+1) (queue: [6 of t+1][2 ph1][2 ph3][4 ph4] -> newest 6 =
// t+2's quarters). Tail: vmcnt(0) at t==NKT-2.
// Epilogue j-inner (R3-proven: WRITE_SIZE 2x -> 1x ideal).
// ---------------------------------------------------------------------------
template<int OUT_BF16>
__device__ __forceinline__ void gemm_tile128(
    const __bf16* __restrict__ X, const __bf16* __restrict__ W,
    const float* __restrict__ bias, void* __restrict__ Yv,
    int m0, int n0, int do_phi)
{
    __shared__ __attribute__((aligned(16))) __bf16 lds[32768]; // 64 KiB
    const int tid  = threadIdx.x;
    const int wave = tid >> 6, lane = tid & 63;
    const int wm = wave >> 1, wn = wave & 1;          // 2 x 2 wave grid
    const int fr = lane & 15, fkb = lane >> 4;        // fragment row / k-block
    const int fsw = fr & 7;                           // read-side XOR swizzle
    const int srow = lane >> 3;                       // staging row in 8-group
    const int sblk = (lane & 7) ^ (srow & 7);         // pre-swizzled src block

    const __bf16* Asrc = X + (size_t)(m0 + wave * 8 + srow) * DIMC + sblk * 8;
    const __bf16* Bsrc = W + (size_t)(n0 + wave * 8 + srow) * DIMC + sblk * 8;

    // one gload issue = 32 rows (quarter tile q); per-wave dest base.
    auto stage = [&](int isB, int q, int kblk, int bb) {
        const __bf16* s = (isB ? Bsrc : Asrc)
                          + (size_t)(q * 32) * DIMC + (size_t)kblk * 64;
        __bf16* d = lds + bb * 16384 + isB * 8192 + q * 2048 + wave * 512;
        __builtin_amdgcn_global_load_lds(
            (const __attribute__((address_space(1))) void*)s,
            (__attribute__((address_space(3))) void*)d, 16, 0, 0);
    };
    // A frag: row wm*64 + i*16 + fr, k-block (ks*4+fkb) XOR row&7
    auto lda = [&](int bb, int i, int ks) -> bf16x8 {
        return *(const bf16x8*)(lds + bb * 16384
                 + (wm * 64 + i * 16 + fr) * 64 + (((ks * 4 + fkb) ^ fsw) * 8));
    };
    auto ldb = [&](int bb, int j, int ks) -> bf16x8 {
        return *(const bf16x8*)(lds + bb * 16384 + 8192
                 + (wn * 64 + j * 16 + fr) * 64 + (((ks * 4 + fkb) ^ fsw) * 8));
    };

    f32x4 acc[4][4] = {};
    bf16x8 a[2][2], b[4][2];

    // prologue: tile0 all 8 quarters + tile1 {B-q0..3, A-q0,q1};
    // A-q2,q3(1) issued at ph1(0). vmcnt(6) keeps exactly tile1's 6.
    stage(1, 0, 0, 0); stage(1, 1, 0, 0); stage(1, 2, 0, 0); stage(1, 3, 0, 0);
    stage(0, 0, 0, 0); stage(0, 1, 0, 0); stage(0, 2, 0, 0); stage(0, 3, 0, 0);
    stage(1, 0, 1, 1); stage(1, 1, 1, 1); stage(1, 2, 1, 1); stage(1, 3, 1, 1);
    stage(0, 0, 1, 1); stage(0, 1, 1, 1);
    asm volatile("s_waitcnt vmcnt(6)" ::: "memory");   // tile 0 resident
    __builtin_amdgcn_s_barrier();

    #pragma unroll 2
    for (int t = 0; t < NKT; ++t) {
        const int buf = t & 1;
        // ---- phase 1: a[0..1], b[0..1]; stage A-q2,q3(t+1)
        #pragma unroll
        for (int i = 0; i < 2; ++i)
            #pragma unroll
            for (int ks = 0; ks < 2; ++ks) a[i][ks] = lda(buf, i, ks);
        #pragma unroll
        for (int j = 0; j < 2; ++j)
            #pragma unroll
            for (int ks = 0; ks < 2; ++ks) b[j][ks] = ldb(buf, j, ks);
        if (t + 1 < NKT) { stage(0, 2, t + 1, buf ^ 1); stage(0, 3, t + 1, buf ^ 1); }
        __builtin_amdgcn_s_barrier();
        asm volatile("s_waitcnt lgkmcnt(0)" ::: "memory");
        __builtin_amdgcn_s_setprio(1);
        #pragma unroll
        for (int i = 0; i < 2; ++i)
            #pragma unroll
            for (int j = 0; j < 2; ++j)
                #pragma unroll
                for (int ks = 0; ks < 2; ++ks)
                    acc[i][j] = MFMA16(a[i][ks], b[j][ks], acc[i][j], 0, 0, 0);
        __builtin_amdgcn_s_setprio(0);
        __builtin_amdgcn_s_barrier();
        // ---- phase 2: b[2..3]
        #pragma unroll
        for (int j = 2; j < 4; ++j)
            #pragma unroll
            for (int ks = 0; ks < 2; ++ks) b[j][ks] = ldb(buf, j, ks);
        __builtin_amdgcn_s_barrier();
        asm volatile("s_waitcnt lgkmcnt(0)" ::: "memory");
        __builtin_amdgcn_s_setprio(1);
        #pragma unroll
        for (int i = 0; i < 2; ++i)
            #pragma unroll
            for (int j = 2; j < 4; ++j)
                #pragma unroll
                for (int ks = 0; ks < 2; ++ks)
                    acc[i][j] = MFMA16(a[i][ks], b[j][ks], acc[i][j], 0, 0, 0);
        __builtin_amdgcn_s_setprio(0);
        __builtin_amdgcn_s_barrier();
        // ---- phase 3: a[2..3] (reuse regs); stage B-q0,q1(t+2)
        #pragma unroll
        for (int i = 0; i < 2; ++i)
            #pragma unroll
            for (int ks = 0; ks < 2; ++ks) a[i][ks] = lda(buf, i + 2, ks);
        if (t + 2 < NKT) { stage(1, 0, t + 2, buf); stage(1, 1, t + 2, buf); }
        __builtin_amdgcn_s_barrier();
        asm volatile("s_waitcnt lgkmcnt(0)" ::: "memory");
        __builtin_amdgcn_s_setprio(1);
        #pragma unroll
        for (int i = 0; i < 2; ++i)
            #pragma unroll
            for (int j = 2; j < 4; ++j)
                #pragma unroll
                for (int ks = 0; ks < 2; ++ks)
                    acc[i + 2][j] = MFMA16(a[i][ks], b[j][ks], acc[i + 2][j], 0, 0, 0);
        __builtin_amdgcn_s_setprio(0);
        __builtin_amdgcn_s_barrier();
        // ---- phase 4: reg-only MFMA; stage B-q2,q3,A-q0,q1(t+2); counted vmcnt
        if (t + 2 < NKT) {
            stage(1, 2, t + 2, buf); stage(1, 3, t + 2, buf);
            stage(0, 0, t + 2, buf); stage(0, 1, t + 2, buf);
        }
        __builtin_amdgcn_s_setprio(1);
        #pragma unroll
        for (int i = 0; i < 2; ++i)
            #pragma unroll
            for (int j = 0; j < 2; ++j)
                #pragma unroll
                for (int ks = 0; ks < 2; ++ks)
                    acc[i + 2][j] = MFMA16(a[i][ks], b[j][ks], acc[i + 2][j], 0, 0, 0);
        __builtin_amdgcn_s_setprio(0);
        if (t < NKT - 2)       asm volatile("s_waitcnt vmcnt(6)" ::: "memory");
        else if (t == NKT - 2) asm volatile("s_waitcnt vmcnt(0)" ::: "memory");
        __builtin_amdgcn_s_barrier();
    }

    // epilogue: C/D layout col=lane&15, row=(lane>>4)*4+reg; j-inner stores.
    const int col_l = lane & 15, quad = lane >> 4;
    const int cbase = n0 + wn * 64 + col_l;
    float bb4[4];
    #pragma unroll
    for (int j = 0; j < 4; ++j) bb4[j] = bias[cbase + j * 16];
    #pragma unroll
    for (int i = 0; i < 4; ++i) {
        #pragma unroll
        for (int r = 0; r < 4; ++r) {
            const size_t grow = (size_t)(m0 + wm * 64 + i * 16 + quad * 4 + r) * DIMC;
            #pragma unroll
            for (int j = 0; j < 4; ++j) {
                float v = acc[i][j][r] + bb4[j];
                if (do_phi) v = phi_f(v);
                if (OUT_BF16)
                    ((__bf16*)Yv)[grow + cbase + j * 16] = (__bf16)v;
                else
                    ((float*)Yv)[grow + cbase + j * 16] = v;
            }
        }
    }
}

// ---------------------------------------------------------------------------
// Fused Q/K/V projection: 3072 blocks = 8 XCD x 3 mat x 16 m x 8 n (128^2
// tiles), matrix-major per-XCD ordering (R1/R4-proven L2 behavior), 2/CU.
// ---------------------------------------------------------------------------
__global__ __launch_bounds__(256, 2) void gemm_qkv(
    const __bf16* __restrict__ X,
    const __bf16* __restrict__ Wq, const __bf16* __restrict__ Wk,
    const __bf16* __restrict__ Wv,
    const float* __restrict__ bq, const float* __restrict__ bk,
    const float* __restrict__ bv,
    __bf16* __restrict__ Q, __bf16* __restrict__ K, __bf16* __restrict__ V)
{
    const int l = blockIdx.x;
    const int xcd = l & 7, s = l >> 3;          // s in [0,384)
    const int mat = s >> 7;                     // 128 blocks per matrix per XCD
    const int t = s & 127;
    const int nb = t & 7;                       // fastest: n-block
    const int m_idx = xcd * 16 + (t >> 3);      // 16 m-panels per XCD
    const __bf16* W = (mat == 0) ? Wq : (mat == 1) ? Wk : Wv;
    const float* bias = (mat == 0) ? bq : (mat == 1) ? bk : bv;
    __bf16* Y = (mat == 0) ? Q : (mat == 1) ? K : V;
    gemm_tile128<1>(X, W, bias, (void*)Y, m_idx * 128, nb * 128, mat != 2);
}

// ---------------------------------------------------------------------------
// Output projection: out = A @ Wo^T + bo (fp32 out). 1024 blocks, 2/CU.
// ---------------------------------------------------------------------------
__global__ __launch_bounds__(256, 2) void gemm_out(
    const __bf16* __restrict__ A, const __bf16* __restrict__ Wo,
    const float* __restrict__ bo, float* __restrict__ out)
{
    const int l = blockIdx.x;
    const int xcd = l & 7, s = l >> 3;          // s in [0,128)
    const int nb = s & 7;
    const int m_idx = xcd * 16 + (s >> 3);
    gemm_tile128<0>(A, Wo, bo, (void*)out, m_idx * 128, nb * 128, 0);
}

// ---------------------------------------------------------------------------
// Per (b,h,split): partial KV[d][e] = sum_n K[n,d]*V[n,e], partial Z[d].
// R4-proven double-buffered LDS (one barrier/chunk, prefetch before barrier).
// ---------------------------------------------------------------------------
__global__ __launch_bounds__(256) void kv_z_kernel(
    const __bf16* __restrict__ Kb, const __bf16* __restrict__ Vb,
    float* __restrict__ P)
{
    __shared__ __attribute__((aligned(16))) __bf16 Kt[2][64 * 36]; // [d][tok]
    __shared__ __attribute__((aligned(16))) __bf16 Vt[2][64 * 36]; // [e][tok]
    __shared__ float zs[64];
    const int tid = threadIdx.x, wave = tid >> 6, lane = tid & 63;
    const int bh = blockIdx.x, b = bh >> 4, h = bh & 15;
    const int split = blockIdx.y;
    const int n0 = split * (SEQ / NSPLIT);
    const int dg = (tid & 15) * 4;     // 4 consecutive dims per thread
    const int u2 = (tid >> 4) * 2;     // token pair
    const int fr = lane & 15, fk = (lane >> 4) * 8;
    const __bf16* Kp = Kb + ((size_t)b * SEQ + n0) * DIMC + h * HD;
    const __bf16* Vp = Vb + ((size_t)b * SEQ + n0) * DIMC + h * HD;
    constexpr int CH = (SEQ / NSPLIT) / 32;   // 16 chunks

    if (tid < 64) zs[tid] = 0.0f;
    f32x4 acc[4] = {};
    float zp[4] = {};

    auto ldc = [&](int c, bf16x4& ka, bf16x4& kb, bf16x4& va, bf16x4& vb) {
        ka = *(const bf16x4*)(Kp + (size_t)(c * 32 + u2) * DIMC + dg);
        kb = *(const bf16x4*)(Kp + (size_t)(c * 32 + u2 + 1) * DIMC + dg);
        va = *(const bf16x4*)(Vp + (size_t)(c * 32 + u2) * DIMC + dg);
        vb = *(const bf16x4*)(Vp + (size_t)(c * 32 + u2 + 1) * DIMC + dg);
    };

    bf16x4 ka, kb, va, vb;
    ldc(0, ka, kb, va, vb);

    for (int c = 0; c < CH; ++c) {
        const int p = c & 1;
        #pragma unroll
        for (int q = 0; q < 4; ++q) {
            zp[q] += (float)ka[q] + (float)kb[q];
            *(bf16x2*)(Kt[p] + (dg + q) * 36 + u2) = bf16x2{ka[q], kb[q]};
            *(bf16x2*)(Vt[p] + (dg + q) * 36 + u2) = bf16x2{va[q], vb[q]};
        }
        bf16x4 nka, nkb, nva, nvb;
        if (c + 1 < CH) ldc(c + 1, nka, nkb, nva, nvb);
        __syncthreads();

        const __bf16* ar = Kt[p] + (wave * 16 + fr) * 36 + fk;
        bf16x4 alo = *(const bf16x4*)ar, ahi = *(const bf16x4*)(ar + 4);
        bf16x8 af = {alo[0],alo[1],alo[2],alo[3],ahi[0],ahi[1],ahi[2],ahi[3]};
        #pragma unroll
        for (int j = 0; j < 4; ++j) {
            const __bf16* br = Vt[p] + (j * 16 + fr) * 36 + fk;
            bf16x4 blo = *(const bf16x4*)br, bhi = *(const bf16x4*)(br + 4);
            bf16x8 bf = {blo[0],blo[1],blo[2],blo[3],bhi[0],bhi[1],bhi[2],bhi[3]};
            acc[j] = __builtin_amdgcn_mfma_f32_16x16x32_bf16(af, bf, acc[j], 0, 0, 0);
        }
        ka = nka; kb = nkb; va = nva; vb = nvb;
    }

    #pragma unroll
    for (int q = 0; q < 4; ++q) atomicAdd(&zs[dg + q], zp[q]);
    __syncthreads();

    float* KVp = P + (size_t)split * PELEMS + bh * 4096;
    const int col_l = lane & 15, quad = lane >> 4;
    #pragma unroll
    for (int j = 0; j < 4; ++j)
        #pragma unroll
        for (int r = 0; r < 4; ++r)
            KVp[(wave * 16 + quad * 4 + r) * 64 + j * 16 + col_l] = acc[j][r];
    if (tid < 64)
        P[(size_t)split * PELEMS + 64 * 64 * 64 + bh * 64 + tid] = zs[tid];
}

// sum NSPLIT partials -> final KV+Z (contiguous PELEMS floats)
__global__ __launch_bounds__(256) void reduce_partials(
    const float* __restrict__ P, float* __restrict__ F)
{
    const int i = blockIdx.x * 256 + threadIdx.x;
    if (i < PELEMS) {
        float s = 0.0f;
        #pragma unroll
        for (int sp = 0; sp < NSPLIT; ++sp) s += P[(size_t)sp * PELEMS + i];
        F[i] = s;
    }
}

// ---------------------------------------------------------------------------
// Per (b,h, 32-token chunk): out[n,e] = (sum_d Q[n,d]*KV[d,e]) / (Q[n]·Z + eps)
// R5: wave-parallel norm — per-thread partial dot from the Q registers it
// already loaded + __shfl_xor reduce over the 8-lane token group. Removes the
// tid<32 serial 64-iter loop (32-way LDS bank conflict, 224 idle lanes), the
// Zs/rnorm LDS buffers, and one barrier.
// ---------------------------------------------------------------------------
__global__ __launch_bounds__(256) void attn_apply(
    const __bf16* __restrict__ Qb, const float* __restrict__ KV,
    const float* __restrict__ Z, __bf16* __restrict__ Ab)
{
    __shared__ __align__(16) float KVs[64][64];
    __shared__ __align__(16) float Qs[32][64];
    const int tid = threadIdx.x;
    const int bh = blockIdx.y;
    const int b = bh >> 4, h = bh & 15;
    const int n0 = blockIdx.x * 32;

    const float* KVp = KV + (size_t)bh * HD * HD;
    #pragma unroll
    for (int r = 0; r < 4; ++r) {
        const int idx = (r * 256 + tid) * 4;
        *(float4*)&((float*)KVs)[idx] = *(const float4*)(KVp + idx);
    }
    const int trow = tid >> 3;
    const int e0 = (tid & 7) * 8;
    const __bf16* Qp = Qb + ((size_t)(b * SEQ + n0)) * DIMC + h * HD;
    float part = 0.0f;
    {
        // this thread's 8 Q values (token trow, dims e0..e0+7)
        bf16x8 q8 = *(const bf16x8*)(Qp + (size_t)trow * DIMC + e0);
        const float* Zp = Z + bh * HD + e0;
        float4 z0 = *(const float4*)Zp, z1 = *(const float4*)(Zp + 4);
        float zf[8] = {z0.x, z0.y, z0.z, z0.w, z1.x, z1.y, z1.z, z1.w};
        #pragma unroll
        for (int q = 0; q < 8; ++q) {
            const float qv = (float)q8[q];
            Qs[trow][e0 + q] = qv;
            part = fmaf(qv, zf[q], part);
        }
    }
    // reduce across the 8 threads owning token trow (consecutive lanes)
    #pragma unroll
    for (int m = 1; m < 8; m <<= 1) part += __shfl_xor(part, m);
    const float rn = 1.0f / (part + EPS);
    __syncthreads();

    float out[8] = {};
    #pragma unroll
    for (int d = 0; d < 64; ++d) {
        const float q = Qs[trow][d];
        #pragma unroll
        for (int j = 0; j < 8; ++j) out[j] = fmaf(q, KVs[d][e0 + j], out[j]);
    }
    __bf16* Op = Ab + ((size_t)(b * SEQ + n0 + trow)) * DIMC + h * HD + e0;
    bf16x8 o;
    #pragma unroll
    for (int j = 0; j < 8; ++j) o[j] = (__bf16)(out[j] * rn);
    *(bf16x8*)Op = o;
}

extern "C" void kernel_launch(void* const* d_in, const int* in_sizes, int n_in,
                              void* d_out, int out_size, void* d_ws, size_t ws_size,
                              hipStream_t stream) {
    const float* x  = (const float*)d_in[0];
    const float* Wq = (const float*)d_in[1];
    const float* bq = (const float*)d_in[2];
    const float* Wk = (const float*)d_in[3];
    const float* bk = (const float*)d_in[4];
    const float* Wv = (const float*)d_in[5];
    const float* bv = (const float*)d_in[6];
    const float* Wo = (const float*)d_in[7];
    const float* bo = (const float*)d_in[8];
    float* out = (float*)d_out;

    const size_t big = (size_t)MTOT * DIMC;     // 16,777,216 elems
    const size_t wsz = (size_t)DIMC * DIMC;     // 1,048,576 elems
    __bf16* wsp = (__bf16*)d_ws;
    __bf16* xb  = wsp;
    __bf16* Wqb = xb + big;
    __bf16* Wkb = Wqb + wsz;
    __bf16* Wvb = Wkb + wsz;
    __bf16* Wob = Wvb + wsz;
    __bf16* Qb  = Wob + wsz;
    __bf16* Kb  = Qb + big;
    __bf16* Vb  = Kb + big;
    __bf16* Ab  = xb;                            // alias: x dead after QKV
    float*  P   = (float*)(Vb + big);            // NSPLIT * PELEMS partials
    float*  F   = P + (size_t)NSPLIT * PELEMS;
    float*  KV  = F;
    float*  Z   = F + 64 * 64 * 64;

    const size_t ntot = big + 4 * wsz;           // 20,971,520 elems
    cvt_all<<<dim3((int)(ntot / 1024)), 256, 0, stream>>>(
        x, Wq, Wk, Wv, Wo, xb, Wqb, Wkb, Wvb, Wob);

    gemm_qkv<<<dim3(3072), 256, 0, stream>>>(
        xb, Wqb, Wkb, Wvb, bq, bk, bv, Qb, Kb, Vb);

    kv_z_kernel<<<dim3(BATCH * NH, NSPLIT), 256, 0, stream>>>(Kb, Vb, P);
    reduce_partials<<<dim3((PELEMS + 255) / 256), 256, 0, stream>>>(P, F);
    attn_apply<<<dim3(SEQ / 32, BATCH * NH), 256, 0, stream>>>(Qb, KV, Z, Ab);

    gemm_out<<<dim3(1024), 256, 0, stream>>>(Ab, Wob, bo, out);
}

// Round 6
// 302.200 us; speedup vs baseline: 1.1576x; 1.1576x over previous
//
#include <hip/hip_runtime.h>
#include <math.h>

#define DIMC 1024
#define SEQ 4096
#define BATCH 4
#define NH 16
#define HD 64
#define MTOT (BATCH * SEQ)      // 16384 rows
#define NSPLIT 8
#define PELEMS (64 * 64 * 64 + 64 * 64)   // KV partial + Z partial per split
#define EPS 1e-6f
#define NKT (DIMC / 64)         // 16 K-tiles of 64

typedef __bf16 bf16x8 __attribute__((ext_vector_type(8)));
typedef __bf16 bf16x4 __attribute__((ext_vector_type(4)));
typedef __bf16 bf16x2 __attribute__((ext_vector_type(2)));
typedef float  f32x4  __attribute__((ext_vector_type(4)));

#define MFMA16 __builtin_amdgcn_mfma_f32_16x16x32_bf16

__device__ __forceinline__ float phi_f(float x) {
    return x > 0.0f ? x + 1.0f : __expf(x);   // elu(x)+1
}

// ---------------------------------------------------------------------------
// One-shot fp32->bf16 conversion of x + all 4 weight matrices.
// ---------------------------------------------------------------------------
__global__ __launch_bounds__(256) void cvt_all(
    const float* __restrict__ x,
    const float* __restrict__ Wq, const float* __restrict__ Wk,
    const float* __restrict__ Wv, const float* __restrict__ Wo,
    __bf16* __restrict__ xb,
    __bf16* __restrict__ Wqb, __bf16* __restrict__ Wkb,
    __bf16* __restrict__ Wvb, __bf16* __restrict__ Wob)
{
    const size_t big = (size_t)MTOT * DIMC;
    const size_t wsz = (size_t)DIMC * DIMC;
    size_t i = ((size_t)blockIdx.x * 256 + threadIdx.x) * 4;
    const float* src; __bf16* dst; size_t off;
    if (i < big) { src = x; dst = xb; off = i; }
    else {
        size_t j = i - big;
        int w = (int)(j >> 20);            // /wsz (2^20)
        off = j & (wsz - 1);
        switch (w) {
            case 0: src = Wq; dst = Wqb; break;
            case 1: src = Wk; dst = Wkb; break;
            case 2: src = Wv; dst = Wvb; break;
            default: src = Wo; dst = Wob; break;
        }
    }
    float4 v = *(const float4*)(src + off);
    bf16x4 o = { (__bf16)v.x, (__bf16)v.y, (__bf16)v.z, (__bf16)v.w };
    *(bf16x4*)(dst + off) = o;
}

// ---------------------------------------------------------------------------
// R4 (best measured) 256x256 8-wave BK=64 GEMM tile, 8-phase counted-vmcnt
// schedule (T2+T3+T4+T5). R5 confirmed 128^2@2/CU is NOT better (110 vs 113
// qkv but worse AI, FETCH +21MB, gemm_out regressed) -> GEMM frozen at R4.
// LDS: 2 buf x {A,B} x 2 row-halves x [128][64] bf16 = 128 KiB.
// Swizzle: linear global_load_lds dest + pre-swizzled GLOBAL source column
// block (blk ^= row&7) + same XOR on ds_read (rule #21; R1: conflicts -> 0).
// Epilogue j-inner (R3-proven: WRITE_SIZE 2x -> 1x ideal = 98.3 MB).
// ---------------------------------------------------------------------------
template<int OUT_BF16>
__device__ __forceinline__ void gemm_tile256(
    const __bf16* __restrict__ X, const __bf16* __restrict__ W,
    const float* __restrict__ bias, void* __restrict__ Yv,
    int m0, int n0, int do_phi)
{
    __shared__ __attribute__((aligned(16))) __bf16 lds[65536]; // 128 KiB
    const int tid  = threadIdx.x;
    const int wave = tid >> 6, lane = tid & 63;
    const int wm = wave >> 2, wn = wave & 3;          // 2 x 4 wave grid
    const int fr = lane & 15, fkb = lane >> 4;        // fragment row / k-block
    const int fsw = fr & 7;                           // read-side XOR swizzle
    const int srow = lane >> 3;                       // staging row in 8-group
    const int sblk = (lane & 7) ^ srow;               // pre-swizzled src block

    const __bf16* Asrc = X + (size_t)(m0 + wave * 8 + srow) * DIMC + sblk * 8;
    const __bf16* Bsrc = W + (size_t)(n0 + wave * 8 + srow) * DIMC + sblk * 8;
    __bf16* lw = lds + wave * 512;   // wave's 8-row slice in each 64-row block

    auto stage = [&](int isB, int h, int kblk, int bb) {
        const __bf16* s = (isB ? Bsrc : Asrc)
                          + (size_t)(h * 128) * DIMC + (size_t)kblk * 64;
        __bf16* d = lw + bb * 32768 + isB * 16384 + h * 8192;
        #pragma unroll
        for (int g = 0; g < 2; ++g)
            __builtin_amdgcn_global_load_lds(
                (const __attribute__((address_space(1))) void*)(s + (size_t)g * 64 * DIMC),
                (__attribute__((address_space(3))) void*)(d + g * 4096),
                16, 0, 0);
    };
    // A frag: rows wm*128 + i*16 + fr, k = ks*32 + fkb*8 (block XOR-swizzled)
    auto lda = [&](int bb, int i, int ks) -> bf16x8 {
        return *(const bf16x8*)(lds + bb * 32768 + wm * 8192
                 + (i * 16 + fr) * 64 + (((ks * 4 + fkb) ^ fsw) * 8));
    };
    // B frag: rows wn*64 + j*16 + fr  (half = wn>>1, local row = (wn&1)*64+..)
    auto ldb = [&](int bb, int j, int ks) -> bf16x8 {
        return *(const bf16x8*)(lds + bb * 32768 + 16384 + (wn >> 1) * 8192
                 + ((wn & 1) * 64 + j * 16 + fr) * 64 + (((ks * 4 + fkb) ^ fsw) * 8));
    };

    f32x4 acc[8][4] = {};
    bf16x8 a[4][2], b[4][2];

    // prologue: tile0 {B0,B1,A0,A1} + tile1 {B0,B1,A0}; A1(1) issued in ph1(0)
    stage(1, 0, 0, 0); stage(1, 1, 0, 0);
    stage(0, 0, 0, 0); stage(0, 1, 0, 0);
    stage(1, 0, 1, 1); stage(1, 1, 1, 1);
    stage(0, 0, 1, 1);
    asm volatile("s_waitcnt vmcnt(6)" ::: "memory");   // tile 0 resident
    __builtin_amdgcn_s_barrier();

    #pragma unroll 2
    for (int t = 0; t < NKT; ++t) {
        const int buf = t & 1;
        // ---- phase 1: A frags 0-3, B frags 0-1; stage A-h1(t+1)
        #pragma unroll
        for (int i = 0; i < 4; ++i)
            #pragma unroll
            for (int ks = 0; ks < 2; ++ks) a[i][ks] = lda(buf, i, ks);
        #pragma unroll
        for (int j = 0; j < 2; ++j)
            #pragma unroll
            for (int ks = 0; ks < 2; ++ks) b[j][ks] = ldb(buf, j, ks);
        if (t + 1 < NKT) stage(0, 1, t + 1, buf ^ 1);
        __builtin_amdgcn_s_barrier();
        asm volatile("s_waitcnt lgkmcnt(0)" ::: "memory");
        __builtin_amdgcn_s_setprio(1);
        #pragma unroll
        for (int i = 0; i < 4; ++i)
            #pragma unroll
            for (int j = 0; j < 2; ++j)
                #pragma unroll
                for (int ks = 0; ks < 2; ++ks)
                    acc[i][j] = MFMA16(a[i][ks], b[j][ks], acc[i][j], 0, 0, 0);
        __builtin_amdgcn_s_setprio(0);
        __builtin_amdgcn_s_barrier();
        // ---- phase 2: B frags 2-3
        #pragma unroll
        for (int j = 2; j < 4; ++j)
            #pragma unroll
            for (int ks = 0; ks < 2; ++ks) b[j][ks] = ldb(buf, j, ks);
        __builtin_amdgcn_s_barrier();
        asm volatile("s_waitcnt lgkmcnt(0)" ::: "memory");
        __builtin_amdgcn_s_setprio(1);
        #pragma unroll
        for (int i = 0; i < 4; ++i)
            #pragma unroll
            for (int j = 2; j < 4; ++j)
                #pragma unroll
                for (int ks = 0; ks < 2; ++ks)
                    acc[i][j] = MFMA16(a[i][ks], b[j][ks], acc[i][j], 0, 0, 0);
        __builtin_amdgcn_s_setprio(0);
        __builtin_amdgcn_s_barrier();
        // ---- phase 3: A frags 4-7; stage B-h0(t+2)
        #pragma unroll
        for (int i = 0; i < 4; ++i)
            #pragma unroll
            for (int ks = 0; ks < 2; ++ks) a[i][ks] = lda(buf, i + 4, ks);
        if (t + 2 < NKT) stage(1, 0, t + 2, buf);
        __builtin_amdgcn_s_barrier();
        asm volatile("s_waitcnt lgkmcnt(0)" ::: "memory");
        __builtin_amdgcn_s_setprio(1);
        #pragma unroll
        for (int i = 0; i < 4; ++i)
            #pragma unroll
            for (int j = 2; j < 4; ++j)
                #pragma unroll
                for (int ks = 0; ks < 2; ++ks)
                    acc[i + 4][j] = MFMA16(a[i][ks], b[j][ks], acc[i + 4][j], 0, 0, 0);
        __builtin_amdgcn_s_setprio(0);
        __builtin_amdgcn_s_barrier();
        // ---- phase 4: stage B-h1(t+2), A-h0(t+2); reg-only MFMA; counted vmcnt
        if (t + 2 < NKT) {
            stage(1, 1, t + 2, buf);
            stage(0, 0, t + 2, buf);
        }
        __builtin_amdgcn_s_setprio(1);
        #pragma unroll
        for (int i = 0; i < 4; ++i)
            #pragma unroll
            for (int j = 0; j < 2; ++j)
                #pragma unroll
                for (int ks = 0; ks < 2; ++ks)
                    acc[i + 4][j] = MFMA16(a[i][ks], b[j][ks], acc[i + 4][j], 0, 0, 0);
        __builtin_amdgcn_s_setprio(0);
        if (t < NKT - 2)       asm volatile("s_waitcnt vmcnt(6)" ::: "memory");
        else if (t == NKT - 2) asm volatile("s_waitcnt vmcnt(0)" ::: "memory");
        __builtin_amdgcn_s_barrier();
    }

    // epilogue: C/D layout col=lane&15, row=(lane>>4)*4+reg; j-inner stores.
    const int col_l = lane & 15, quad = lane >> 4;
    const int cbase = n0 + wn * 64 + col_l;
    float bb4[4];
    #pragma unroll
    for (int j = 0; j < 4; ++j) bb4[j] = bias[cbase + j * 16];
    #pragma unroll
    for (int i = 0; i < 8; ++i) {
        #pragma unroll
        for (int r = 0; r < 4; ++r) {
            const size_t grow = (size_t)(m0 + wm * 128 + i * 16 + quad * 4 + r) * DIMC;
            #pragma unroll
            for (int j = 0; j < 4; ++j) {
                float v = acc[i][j][r] + bb4[j];
                if (do_phi) v = phi_f(v);
                if (OUT_BF16)
                    ((__bf16*)Yv)[grow + cbase + j * 16] = (__bf16)v;
                else
                    ((float*)Yv)[grow + cbase + j * 16] = v;
            }
        }
    }
}

// ---------------------------------------------------------------------------
// Fused Q/K/V projection, R4 grid: 768 blocks = 8 XCD x 3 mat x 8 m x 4 n.
// Matrix-major per-XCD ordering keeps W_mat (2 MB) L2-hot; X panels stream.
// ---------------------------------------------------------------------------
__global__ __launch_bounds__(512, 2) void gemm_qkv(
    const __bf16* __restrict__ X,
    const __bf16* __restrict__ Wq, const __bf16* __restrict__ Wk,
    const __bf16* __restrict__ Wv,
    const float* __restrict__ bq, const float* __restrict__ bk,
    const float* __restrict__ bv,
    __bf16* __restrict__ Q, __bf16* __restrict__ K, __bf16* __restrict__ V)
{
    const int l = blockIdx.x;
    const int xcd = l & 7, s = l >> 3;          // s in [0,96)
    const int mat = s >> 5;                     // 32 blocks per matrix per XCD
    const int t = s & 31;
    const int nb = t & 3;                       // fastest: n-block
    const int m_idx = xcd * 8 + (t >> 2);       // 8 m-panels per XCD
    const __bf16* W = (mat == 0) ? Wq : (mat == 1) ? Wk : Wv;
    const float* bias = (mat == 0) ? bq : (mat == 1) ? bk : bv;
    __bf16* Y = (mat == 0) ? Q : (mat == 1) ? K : V;
    gemm_tile256<1>(X, W, bias, (void*)Y, m_idx * 256, nb * 256, mat != 2);
}

// ---------------------------------------------------------------------------
// Output projection: out = A @ Wo^T + bo (fp32 out). 256 blocks = 1/CU.
// ---------------------------------------------------------------------------
__global__ __launch_bounds__(512, 2) void gemm_out(
    const __bf16* __restrict__ A, const __bf16* __restrict__ Wo,
    const float* __restrict__ bo, float* __restrict__ out)
{
    const int l = blockIdx.x;
    const int xcd = l & 7, s = l >> 3;          // s in [0,32)
    const int m_idx = xcd * 8 + (s >> 2);
    const int nb = s & 3;
    gemm_tile256<0>(A, Wo, bo, (void*)out, m_idx * 256, nb * 256, 0);
}

// ---------------------------------------------------------------------------
// Per (b,h,split): partial KV[d][e] = sum_n K[n,d]*V[n,e], partial Z[d].
// R4-proven double-buffered LDS (one barrier/chunk, prefetch before barrier).
// ---------------------------------------------------------------------------
__global__ __launch_bounds__(256) void kv_z_kernel(
    const __bf16* __restrict__ Kb, const __bf16* __restrict__ Vb,
    float* __restrict__ P)
{
    __shared__ __attribute__((aligned(16))) __bf16 Kt[2][64 * 36]; // [d][tok]
    __shared__ __attribute__((aligned(16))) __bf16 Vt[2][64 * 36]; // [e][tok]
    __shared__ float zs[64];
    const int tid = threadIdx.x, wave = tid >> 6, lane = tid & 63;
    const int bh = blockIdx.x, b = bh >> 4, h = bh & 15;
    const int split = blockIdx.y;
    const int n0 = split * (SEQ / NSPLIT);
    const int dg = (tid & 15) * 4;     // 4 consecutive dims per thread
    const int u2 = (tid >> 4) * 2;     // token pair
    const int fr = lane & 15, fk = (lane >> 4) * 8;
    const __bf16* Kp = Kb + ((size_t)b * SEQ + n0) * DIMC + h * HD;
    const __bf16* Vp = Vb + ((size_t)b * SEQ + n0) * DIMC + h * HD;
    constexpr int CH = (SEQ / NSPLIT) / 32;   // 16 chunks

    if (tid < 64) zs[tid] = 0.0f;
    f32x4 acc[4] = {};
    float zp[4] = {};

    auto ldc = [&](int c, bf16x4& ka, bf16x4& kb, bf16x4& va, bf16x4& vb) {
        ka = *(const bf16x4*)(Kp + (size_t)(c * 32 + u2) * DIMC + dg);
        kb = *(const bf16x4*)(Kp + (size_t)(c * 32 + u2 + 1) * DIMC + dg);
        va = *(const bf16x4*)(Vp + (size_t)(c * 32 + u2) * DIMC + dg);
        vb = *(const bf16x4*)(Vp + (size_t)(c * 32 + u2 + 1) * DIMC + dg);
    };

    bf16x4 ka, kb, va, vb;
    ldc(0, ka, kb, va, vb);

    for (int c = 0; c < CH; ++c) {
        const int p = c & 1;
        #pragma unroll
        for (int q = 0; q < 4; ++q) {
            zp[q] += (float)ka[q] + (float)kb[q];
            *(bf16x2*)(Kt[p] + (dg + q) * 36 + u2) = bf16x2{ka[q], kb[q]};
            *(bf16x2*)(Vt[p] + (dg + q) * 36 + u2) = bf16x2{va[q], vb[q]};
        }
        bf16x4 nka, nkb, nva, nvb;
        if (c + 1 < CH) ldc(c + 1, nka, nkb, nva, nvb);
        __syncthreads();

        const __bf16* ar = Kt[p] + (wave * 16 + fr) * 36 + fk;
        bf16x4 alo = *(const bf16x4*)ar, ahi = *(const bf16x4*)(ar + 4);
        bf16x8 af = {alo[0],alo[1],alo[2],alo[3],ahi[0],ahi[1],ahi[2],ahi[3]};
        #pragma unroll
        for (int j = 0; j < 4; ++j) {
            const __bf16* br = Vt[p] + (j * 16 + fr) * 36 + fk;
            bf16x4 blo = *(const bf16x4*)br, bhi = *(const bf16x4*)(br + 4);
            bf16x8 bf = {blo[0],blo[1],blo[2],blo[3],bhi[0],bhi[1],bhi[2],bhi[3]};
            acc[j] = __builtin_amdgcn_mfma_f32_16x16x32_bf16(af, bf, acc[j], 0, 0, 0);
        }
        ka = nka; kb = nkb; va = nva; vb = nvb;
    }

    #pragma unroll
    for (int q = 0; q < 4; ++q) atomicAdd(&zs[dg + q], zp[q]);
    __syncthreads();

    float* KVp = P + (size_t)split * PELEMS + bh * 4096;
    const int col_l = lane & 15, quad = lane >> 4;
    #pragma unroll
    for (int j = 0; j < 4; ++j)
        #pragma unroll
        for (int r = 0; r < 4; ++r)
            KVp[(wave * 16 + quad * 4 + r) * 64 + j * 16 + col_l] = acc[j][r];
    if (tid < 64)
        P[(size_t)split * PELEMS + 64 * 64 * 64 + bh * 64 + tid] = zs[tid];
}

// sum NSPLIT partials -> final KV+Z (contiguous PELEMS floats)
__global__ __launch_bounds__(256) void reduce_partials(
    const float* __restrict__ P, float* __restrict__ F)
{
    const int i = blockIdx.x * 256 + threadIdx.x;
    if (i < PELEMS) {
        float s = 0.0f;
        #pragma unroll
        for (int sp = 0; sp < NSPLIT; ++sp) s += P[(size_t)sp * PELEMS + i];
        F[i] = s;
    }
}

// ---------------------------------------------------------------------------
// R6 attn_apply: MFMA-based PV. Per (b,h, 128-token chunk):
//   out[n,e] = (sum_d Q[n,d]*KV[d,e]) / (Q[n]·Z + eps)
// Old version: 8192 blocks x 16KB KV re-read (131 MB L2/L3 traffic) + f32
// VALU inner product (matmul-shaped compute off the matrix cores). New:
// 2048 blocks (4x fewer KV reloads -> 33 MB), KV transposed in LDS and split
// into bf16 hi/lo planes (two MFMAs accumulate Q@(hi+lo): ~17-bit effective
// mantissa, preserves current absmax headroom), wave-parallel norm via
// __shfl_xor, per-row rescale gathered with __shfl in the epilogue.
// LDS padded to 80 cols (160B rows, 16B-aligned for b128; 4-way bank alias
// on the few frag reads -- negligible here).
// ---------------------------------------------------------------------------
__global__ __launch_bounds__(256) void attn_apply(
    const __bf16* __restrict__ Qb, const float* __restrict__ F,
    __bf16* __restrict__ Ab)
{
    __shared__ __align__(16) float  Ftmp[4096];      // KV f32 [d][e]
    __shared__ __align__(16) __bf16 KVhi[64 * 80];   // [e][d] padded
    __shared__ __align__(16) __bf16 KVlo[64 * 80];
    __shared__ __align__(16) __bf16 Qs[128 * 80];    // [tok][d] padded
    const int tid = threadIdx.x, wave = tid >> 6, lane = tid & 63;
    const int bhh = blockIdx.y, b = bhh >> 4, h = bhh & 15;
    const int n0 = blockIdx.x * 128;

    // 1) stage KV f32 (coalesced) + issue Q loads into regs
    const float* KVp = F + (size_t)bhh * 4096;
    #pragma unroll
    for (int r = 0; r < 4; ++r) {
        const int idx = (r * 256 + tid) * 4;
        *(float4*)&Ftmp[idx] = *(const float4*)(KVp + idx);
    }
    const __bf16* Qp = Qb + ((size_t)(b * SEQ + n0)) * DIMC + h * HD;
    const int qrow = tid >> 3, qcol = (tid & 7) * 8;
    bf16x8 qv[4];
    #pragma unroll
    for (int rr = 0; rr < 4; ++rr)
        qv[rr] = *(const bf16x8*)(Qp + (size_t)(rr * 32 + qrow) * DIMC + qcol);
    __syncthreads();

    // 2) transpose + hi/lo split (thread: e = tid>>2, d-block = (tid&3)*16);
    //    write Q regs into padded LDS.
    {
        const int e = tid >> 2, d0 = (tid & 3) * 16;
        #pragma unroll
        for (int k = 0; k < 16; k += 2) {
            float v0 = Ftmp[(d0 + k) * 64 + e];
            float v1 = Ftmp[(d0 + k + 1) * 64 + e];
            __bf16 h0 = (__bf16)v0, h1 = (__bf16)v1;
            *(bf16x2*)(KVhi + e * 80 + d0 + k) = bf16x2{h0, h1};
            *(bf16x2*)(KVlo + e * 80 + d0 + k) =
                bf16x2{(__bf16)(v0 - (float)h0), (__bf16)(v1 - (float)h1)};
        }
        #pragma unroll
        for (int rr = 0; rr < 4; ++rr)
            *(bf16x8*)(Qs + (rr * 32 + qrow) * 80 + qcol) = qv[rr];
    }
    __syncthreads();

    // 3) norm: token tt = lane&31 (lane and lane+32 split the 64 dims)
    const int tt = lane & 31, half = lane >> 5;
    float part = 0.0f;
    const float* Zp = F + 64 * 64 * 64 + bhh * HD + half * 32;
    #pragma unroll
    for (int g = 0; g < 4; ++g) {
        bf16x8 q8 = *(const bf16x8*)(Qs + (wave * 32 + tt) * 80 + half * 32 + g * 8);
        float4 z0 = *(const float4*)(Zp + g * 8);
        float4 z1 = *(const float4*)(Zp + g * 8 + 4);
        part = fmaf((float)q8[0], z0.x, part);
        part = fmaf((float)q8[1], z0.y, part);
        part = fmaf((float)q8[2], z0.z, part);
        part = fmaf((float)q8[3], z0.w, part);
        part = fmaf((float)q8[4], z1.x, part);
        part = fmaf((float)q8[5], z1.y, part);
        part = fmaf((float)q8[6], z1.z, part);
        part = fmaf((float)q8[7], z1.w, part);
    }
    part += __shfl_xor(part, 32);
    const float rn = 1.0f / (part + EPS);

    // 4) MFMA: wave's 32 tokens x 64 e-cols, K=64 over d; hi+lo accumulate
    const int fr = lane & 15, fkb = lane >> 4;
    f32x4 acc[2][4] = {};
    #pragma unroll
    for (int ks = 0; ks < 2; ++ks) {
        bf16x8 a0 = *(const bf16x8*)(Qs + (wave * 32 + fr) * 80 + ks * 32 + fkb * 8);
        bf16x8 a1 = *(const bf16x8*)(Qs + (wave * 32 + 16 + fr) * 80 + ks * 32 + fkb * 8);
        #pragma unroll
        for (int j = 0; j < 4; ++j) {
            bf16x8 bh8 = *(const bf16x8*)(KVhi + (j * 16 + fr) * 80 + ks * 32 + fkb * 8);
            bf16x8 bl8 = *(const bf16x8*)(KVlo + (j * 16 + fr) * 80 + ks * 32 + fkb * 8);
            acc[0][j] = MFMA16(a0, bh8, acc[0][j], 0, 0, 0);
            acc[0][j] = MFMA16(a0, bl8, acc[0][j], 0, 0, 0);
            acc[1][j] = MFMA16(a1, bh8, acc[1][j], 0, 0, 0);
            acc[1][j] = MFMA16(a1, bl8, acc[1][j], 0, 0, 0);
        }
    }

    // 5) epilogue: C/D layout col=lane&15, row=(lane>>4)*4+r; rescale by rn
    const int col_l = lane & 15, quad = lane >> 4;
    #pragma unroll
    for (int i = 0; i < 2; ++i) {
        #pragma unroll
        for (int r = 0; r < 4; ++r) {
            const float rni = __shfl(rn, i * 16 + quad * 4 + r);
            const int tok = n0 + wave * 32 + i * 16 + quad * 4 + r;
            __bf16* Op = Ab + ((size_t)(b * SEQ + tok)) * DIMC + h * HD + col_l;
            #pragma unroll
            for (int j = 0; j < 4; ++j)
                Op[j * 16] = (__bf16)(acc[i][j][r] * rni);
        }
    }
}

extern "C" void kernel_launch(void* const* d_in, const int* in_sizes, int n_in,
                              void* d_out, int out_size, void* d_ws, size_t ws_size,
                              hipStream_t stream) {
    const float* x  = (const float*)d_in[0];
    const float* Wq = (const float*)d_in[1];
    const float* bq = (const float*)d_in[2];
    const float* Wk = (const float*)d_in[3];
    const float* bk = (const float*)d_in[4];
    const float* Wv = (const float*)d_in[5];
    const float* bv = (const float*)d_in[6];
    const float* Wo = (const float*)d_in[7];
    const float* bo = (const float*)d_in[8];
    float* out = (float*)d_out;

    const size_t big = (size_t)MTOT * DIMC;     // 16,777,216 elems
    const size_t wsz = (size_t)DIMC * DIMC;     // 1,048,576 elems
    __bf16* wsp = (__bf16*)d_ws;
    __bf16* xb  = wsp;
    __bf16* Wqb = xb + big;
    __bf16* Wkb = Wqb + wsz;
    __bf16* Wvb = Wkb + wsz;
    __bf16* Wob = Wvb + wsz;
    __bf16* Qb  = Wob + wsz;
    __bf16* Kb  = Qb + big;
    __bf16* Vb  = Kb + big;
    __bf16* Ab  = xb;                            // alias: x dead after QKV
    float*  P   = (float*)(Vb + big);            // NSPLIT * PELEMS partials
    float*  F   = P + (size_t)NSPLIT * PELEMS;

    const size_t ntot = big + 4 * wsz;           // 20,971,520 elems
    cvt_all<<<dim3((int)(ntot / 1024)), 256, 0, stream>>>(
        x, Wq, Wk, Wv, Wo, xb, Wqb, Wkb, Wvb, Wob);

    gemm_qkv<<<dim3(768), 512, 0, stream>>>(
        xb, Wqb, Wkb, Wvb, bq, bk, bv, Qb, Kb, Vb);

    kv_z_kernel<<<dim3(BATCH * NH, NSPLIT), 256, 0, stream>>>(Kb, Vb, P);
    reduce_partials<<<dim3((PELEMS + 255) / 256), 256, 0, stream>>>(P, F);
    attn_apply<<<dim3(SEQ / 128, BATCH * NH), 256, 0, stream>>>(Qb, F, Ab);

    gemm_out<<<dim3(256), 512, 0, stream>>>(Ab, Wob, bo, out);
}